// Round 1
// baseline (230.066 us; speedup 1.0000x reference)
//
#include <hip/hip_runtime.h>

// ReluGalois: y = Horner(coeff, x), degree 8 (9 coefficients), float32 in/out.
// Shape (8, 2048, 2048) = 33,554,432 elements — divisible by 4, so float4
// vectorization has no tail. Memory-bound: 8 B/elem traffic, 8 FMA/elem.

#define NCOEF 9

__global__ __launch_bounds__(256) void relu_galois_poly(
    const float* __restrict__ x,
    const float* __restrict__ coeff,
    float* __restrict__ out,
    int n4)  // number of float4 elements
{
    // Hoist coefficients to registers. Uniform address across lanes ->
    // broadcast from L1/L2; executed once per thread before the loop.
    float c[NCOEF];
#pragma unroll
    for (int i = 0; i < NCOEF; ++i) c[i] = coeff[i];

    const int stride = gridDim.x * blockDim.x;
    for (int i = blockIdx.x * blockDim.x + threadIdx.x; i < n4; i += stride) {
        float4 v = reinterpret_cast<const float4*>(x)[i];
        // 4 independent Horner chains per lane -> ILP hides FMA latency.
        float a0 = c[0], a1 = c[0], a2 = c[0], a3 = c[0];
#pragma unroll
        for (int k = 1; k < NCOEF; ++k) {
            a0 = fmaf(a0, v.x, c[k]);
            a1 = fmaf(a1, v.y, c[k]);
            a2 = fmaf(a2, v.z, c[k]);
            a3 = fmaf(a3, v.w, c[k]);
        }
        float4 r;
        r.x = a0; r.y = a1; r.z = a2; r.w = a3;
        reinterpret_cast<float4*>(out)[i] = r;
    }
}

extern "C" void kernel_launch(void* const* d_in, const int* in_sizes, int n_in,
                              void* d_out, int out_size, void* d_ws, size_t ws_size,
                              hipStream_t stream) {
    const float* x     = (const float*)d_in[0];
    const float* coeff = (const float*)d_in[1];
    float* out         = (float*)d_out;

    const int n  = in_sizes[0];      // 33,554,432
    const int n4 = n / 4;            // 8,388,608 float4s (exact)

    const int block = 256;
    // Memory-bound: cap grid at ~8 blocks/CU x 256 CUs and grid-stride.
    int grid = (n4 + block - 1) / block;
    if (grid > 2048) grid = 2048;

    relu_galois_poly<<<grid, block, 0, stream>>>(x, coeff, out, n4);
}